// Round 7
// baseline (436.897 us; speedup 1.0000x reference)
//
#include <hip/hip_runtime.h>

// Problem constants (match reference)
#define D     4
#define MUL   16
#define S0    8
#define S1    8
#define SOUT  8
#define NP3   8
#define NP4   4

#define EPB   32          // 32 edges per block: each wave owns 2 edge-quads (A,B)
#define TPB   256
// Wt row stride per edge: 192 entries + 8 pad = 200 floats = 800 B.
#define WSTRIDE 200

// Wave-scope LDS ordering: producers and consumers of each Wt row are the SAME
// wave, and DS ops from one wave execute in order. Stop compiler reordering only.
__device__ __forceinline__ void wave_lds_fence() {
    __builtin_amdgcn_fence(__ATOMIC_RELEASE, "wavefront");
    __builtin_amdgcn_wave_barrier();
    __builtin_amdgcn_fence(__ATOMIC_ACQUIRE, "wavefront");
}

// DPP quad butterfly add: sums over the 4 lanes of each quad (lane&3 = j).
__device__ __forceinline__ float dpp_add_xor1(float v) {
    int y = __builtin_amdgcn_update_dpp(0, __float_as_int(v), 0xB1, 0xF, 0xF, true);
    return v + __int_as_float(y);
}
__device__ __forceinline__ float dpp_add_xor2(float v) {
    int y = __builtin_amdgcn_update_dpp(0, __float_as_int(v), 0x4E, 0xF, 0xF, true);
    return v + __int_as_float(y);
}
__device__ __forceinline__ float4 quad_sum4(float4 v) {
    v.x = dpp_add_xor1(v.x); v.y = dpp_add_xor1(v.y);
    v.z = dpp_add_xor1(v.z); v.w = dpp_add_xor1(v.w);
    v.x = dpp_add_xor2(v.x); v.y = dpp_add_xor2(v.y);
    v.z = dpp_add_xor2(v.z); v.w = dpp_add_xor2(v.w);
    return v;
}

// Per-lane component select v[j] (j divergent) -> 3 v_cndmask, no scratch.
__device__ __forceinline__ float comp_sel(float4 v, int j) {
    const float lo = (j & 1) ? v.y : v.x;
    const float hi = (j & 1) ? v.w : v.z;
    return (j & 2) ? hi : lo;
}

__device__ __forceinline__ float4 sel8(const float4 (&a)[8], int s) {
    switch (s & 7) {
        case 0: return a[0];
        case 1: return a[1];
        case 2: return a[2];
        case 3: return a[3];
        case 4: return a[4];
        case 5: return a[5];
        case 6: return a[6];
        default: return a[7];
    }
}

#define ADDC4(idx) acc[idx].x += cv.x; acc[idx].y += cv.y; acc[idx].z += cv.z; acc[idx].w += cv.w; break;
__device__ __forceinline__ void addsel4(float4 (&acc)[4], int s, float4 cv) {
    switch (s & 3) {
        case 0: ADDC4(0)
        case 1: ADDC4(1)
        case 2: ADDC4(2)
        default: ADDC4(3)
    }
}

// Build one edge's 12 weight rows into wr (R6's lane-cooperative scheme).
__device__ __forceinline__ void build_wt(float* __restrict__ wr,
                                         const float* __restrict__ x1r,
                                         const int (&q3s1)[NP3],
                                         const int (&q4s1)[NP4],
                                         const int (&q4s2)[NP4],
                                         const float* __restrict__ C3,
                                         const float* __restrict__ C4,
                                         int u, int j, int iu)
{
    #pragma unroll
    for (int p = 0; p < NP3; ++p) {
        const float4 b   = *(const float4*)(x1r + q3s1[p] * D);
        const float4 c3v = *(const float4*)(C3 + p * 64 + u * 4); // C3[p][i][j][:]
        const float bs = comp_sel(b, j);
        float4 part = make_float4(bs * c3v.x, bs * c3v.y, bs * c3v.z, bs * c3v.w);
        part = quad_sum4(part);                   // sum over j across the quad
        if (j == 0) *(float4*)(wr + p * 16 + iu * 4) = part;  // W3[i][k]
    }
    #pragma unroll
    for (int p = 0; p < NP4; ++p) {
        const float4 b = *(const float4*)(x1r + q4s1[p] * D);
        const float4 c = *(const float4*)(x1r + q4s2[p] * D);
        const float* c4 = C4 + p * 256 + u * 16;  // C4[p][i][j][k][:]
        const float4 v0 = *(const float4*)(c4 + 0);
        const float4 v1 = *(const float4*)(c4 + 4);
        const float4 v2 = *(const float4*)(c4 + 8);
        const float4 v3 = *(const float4*)(c4 + 12);
        float4 t;
        t.x = c.x * v0.x + c.y * v1.x + c.z * v2.x + c.w * v3.x;
        t.y = c.x * v0.y + c.y * v1.y + c.z * v2.y + c.w * v3.y;
        t.z = c.x * v0.z + c.y * v1.z + c.z * v2.z + c.w * v3.z;
        t.w = c.x * v0.w + c.y * v1.w + c.z * v2.w + c.w * v3.w;
        const float bs = comp_sel(b, j);
        t.x *= bs; t.y *= bs; t.z *= bs; t.w *= bs;
        t = quad_sum4(t);                          // sum over j across the quad
        if (j == 0) *(float4*)(wr + 128 + p * 16 + iu * 4) = t;  // W4[i][m]
    }
}

// Contribute one edge's 12 paths (two output-slot halves) and store.
__device__ __forceinline__ void contribute_store(const float4 (&a)[S0],
                                                 const float* __restrict__ wr,
                                                 const int (&q3s0)[NP3], const int (&q3so)[NP3],
                                                 const int (&q4s0)[NP4], const int (&q4so)[NP4],
                                                 float* __restrict__ o, bool ev, int u)
{
    #pragma unroll
    for (int h = 0; h < 2; ++h) {
        float4 acc[4];
        #pragma unroll
        for (int s = 0; s < 4; ++s) acc[s] = make_float4(0.f, 0.f, 0.f, 0.f);

        #pragma unroll
        for (int p = 0; p < NP3 + NP4; ++p) {
            const int s0s = (p < NP3) ? q3s0[p] : q4s0[p - NP3];
            const int os  = (p < NP3) ? q3so[p] : q4so[p - NP3];
            if ((os >> 2) == h) {               // wave-uniform branch (SGPR)
                const float4 av = sel8(a, s0s);
                const float4 w0  = *(const float4*)(wr + p * 16 + 0);
                const float4 w1  = *(const float4*)(wr + p * 16 + 4);
                const float4 w2  = *(const float4*)(wr + p * 16 + 8);
                const float4 w3v = *(const float4*)(wr + p * 16 + 12);
                float4 cv;
                cv.x = av.x * w0.x + av.y * w1.x + av.z * w2.x + av.w * w3v.x;
                cv.y = av.x * w0.y + av.y * w1.y + av.z * w2.y + av.w * w3v.y;
                cv.z = av.x * w0.z + av.y * w1.z + av.z * w2.z + av.w * w3v.z;
                cv.w = av.x * w0.w + av.y * w1.w + av.z * w2.w + av.w * w3v.w;
                addsel4(acc, os, cv);
            }
        }

        if (ev) {
            #pragma unroll
            for (int s = 0; s < 4; ++s) {
                *(float4*)(o + ((h * 4 + s) * MUL + u) * D) = acc[s];
            }
        }
    }
}

// 4 waves/EU floor -> VGPR cap 128: two gathers in flight (aA+aB = 64 regs) +
// acc[4] + transients ~= 110 live peak; split-acc halves (R5) keep windows small.
__global__ __launch_bounds__(TPB, 4)
void tp_fused_kernel(const float* __restrict__ x0,
                     const int*   __restrict__ i0,
                     const float* __restrict__ x1,
                     const float* __restrict__ C3,
                     const float* __restrict__ C4,
                     const int*   __restrict__ p3,
                     const int*   __restrict__ p4,
                     float*       __restrict__ out,
                     int E)
{
    __shared__ float Wt[EPB * WSTRIDE];   // 25.6 KB: 32 edges x 12 weight rows

    const int tid = threadIdx.x;
    const int eL  = tid >> 4;        // local edge 0..15 (quad slot within half)
    const int u   = tid & 15;        // mul channel 0..15
    const long eA = (long)blockIdx.x * EPB + eL;
    const long eB = eA + 16;
    const bool evA = (eA < (long)E);
    const bool evB = (eB < (long)E);
    const long ecA = evA ? eA : (long)(E - 1);
    const long ecB = evB ? eB : (long)(E - 1);

    // ---------- issue BOTH gather chains first: 16 outstanding loads ----------
    const int rowA = i0[ecA];
    const int rowB = i0[ecB];
    const float4* arA = (const float4*)(x0 + (long)rowA * (S0 * MUL * D));
    const float4* arB = (const float4*)(x0 + (long)rowB * (S0 * MUL * D));
    float4 aA[S0], aB[S0];
    #pragma unroll
    for (int s = 0; s < S0; ++s) aA[s] = arA[s * MUL + u];
    #pragma unroll
    for (int s = 0; s < S0; ++s) aB[s] = arB[s * MUL + u];

    // ---------- path metadata: uniform addresses -> s_load into SGPRs ----------
    int q3s0[NP3], q3s1[NP3], q3so[NP3];
    #pragma unroll
    for (int p = 0; p < NP3; ++p) {
        q3s0[p] = p3[p * 3 + 0];
        q3s1[p] = p3[p * 3 + 1];
        q3so[p] = p3[p * 3 + 2];
    }
    int q4s0[NP4], q4s1[NP4], q4s2[NP4], q4so[NP4];
    #pragma unroll
    for (int p = 0; p < NP4; ++p) {
        q4s0[p] = p4[p * 4 + 0];
        q4s1[p] = p4[p * 4 + 1];
        q4s2[p] = p4[p * 4 + 2];
        q4so[p] = p4[p * 4 + 3];
    }

    // ---------- weight matrices for both edges (overlaps gather latency) ----------
    const int j  = u & 3;
    const int iu = u >> 2;
    float* wrA = &Wt[eL * WSTRIDE];
    float* wrB = &Wt[(16 + eL) * WSTRIDE];

    build_wt(wrA, x1 + ecA * (S1 * D), q3s1, q4s1, q4s2, C3, C4, u, j, iu);
    build_wt(wrB, x1 + ecB * (S1 * D), q3s1, q4s1, q4s2, C3, C4, u, j, iu);

    wave_lds_fence();   // same-wave producers/consumers; no s_barrier

    // ---------- contribute A (waits only its vmcnt slice), then B ----------
    // B's gather latency hides under A's LDS reads + FMAs.
    contribute_store(aA, wrA, q3s0, q3so, q4s0, q4so,
                     out + eA * (SOUT * MUL * D), evA, u);
    contribute_store(aB, wrB, q3s0, q3so, q4s0, q4so,
                     out + eB * (SOUT * MUL * D), evB, u);
}

extern "C" void kernel_launch(void* const* d_in, const int* in_sizes, int n_in,
                              void* d_out, int out_size, void* d_ws, size_t ws_size,
                              hipStream_t stream) {
    const float* x0 = (const float*)d_in[0];
    const int*   i0 = (const int*)  d_in[1];
    const float* x1 = (const float*)d_in[2];
    const float* C3 = (const float*)d_in[3];
    const float* C4 = (const float*)d_in[4];
    const int*   p3 = (const int*)  d_in[5];
    const int*   p4 = (const int*)  d_in[6];
    float* out = (float*)d_out;

    const int E = in_sizes[1];                 // i0 has E elements
    const int blocks = (E + EPB - 1) / EPB;
    tp_fused_kernel<<<blocks, TPB, 0, stream>>>(x0, i0, x1, C3, C4, p3, p4, out, E);
}